// Round 4
// baseline (7762.003 us; speedup 1.0000x reference)
//
#include <hip/hip_runtime.h>

// Problem constants
#define BB 4
#define SS 1024
#define HH 768
#define NH 12
#define DD 64
#define SPAN 256      // BUCKETS
#define TWOSPAN 512
#define TOT (BB * SS * HH)              // 3,145,728
#define POSTOT (TWOSPAN * HH)           // 393,216
#define WTOT (HH * HH)                  // 589,824

typedef unsigned short u16;

// ---------------------------------------------------------------------------
// Static device storage.  Input mirrors (bf16) + computed tensors (bf16).
// All fully rewritten every launch before being read.
// ---------------------------------------------------------------------------
__device__ u16 g_hid[TOT];
__device__ u16 g_rel[POSTOT];
__device__ u16 g_Wq[WTOT];
__device__ u16 g_Wk[WTOT];
__device__ u16 g_Wv[WTOT];
__device__ u16 g_Wo[WTOT];
__device__ u16 g_bq[HH];
__device__ u16 g_bk[HH];
__device__ u16 g_bv[HH];
__device__ u16 g_bo[HH];
__device__ u16 g_lnw[HH];
__device__ u16 g_lnb[HH];

__device__ u16 g_q[TOT];
__device__ u16 g_k[TOT];
__device__ u16 g_v[TOT];
__device__ u16 g_ctx[TOT];
__device__ u16 g_posk[POSTOT];
__device__ u16 g_posq[POSTOT];
__device__ int g_relidx[2048];
__device__ int g_isfp32;

__device__ __forceinline__ float b2f(u16 u) {
    union { unsigned int i; float f; } x;
    x.i = ((unsigned int)u) << 16;
    return x.f;
}
// fp32 -> bf16 round-to-nearest-even
__device__ __forceinline__ u16 f2b(float f) {
    union { float f; unsigned int i; } x;
    x.f = f;
    unsigned int r = x.i + 0x7fffu + ((x.i >> 16) & 1u);
    return (u16)(r >> 16);
}

// ---------------------------------------------------------------------------
// Kernel 0: input dtype detection.  hidden ~ N(0,1).  If the buffer is bf16,
// every u16 is a bf16 value with |x| < 8 (exp field < 130).  If it is fp32,
// even-index u16s are low mantissa bits: ~49% have exp field >= 130.
// ---------------------------------------------------------------------------
__global__ void detect_dtype(const u16* __restrict__ hid) {
    __shared__ int cnt;
    if (threadIdx.x == 0) cnt = 0;
    __syncthreads();
    const u16 u = hid[threadIdx.x * 2];
    const int e = (u >> 7) & 0xFF;
    if (e >= 130) atomicAdd(&cnt, 1);
    __syncthreads();
    if (threadIdx.x == 0) g_isfp32 = (cnt >= 16) ? 1 : 0;
}

// ---------------------------------------------------------------------------
// Kernel 0b: convert an input tensor into its bf16 mirror.
// ---------------------------------------------------------------------------
__global__ void convert_in(const void* __restrict__ src, u16* __restrict__ dst, int n) {
    const int i = blockIdx.x * blockDim.x + threadIdx.x;
    if (i >= n) return;
    if (g_isfp32) dst[i] = f2b(((const float*)src)[i]);
    else          dst[i] = ((const u16*)src)[i];
}

// ---------------------------------------------------------------------------
// Kernel 1: relative-position bucket index table.
// ---------------------------------------------------------------------------
__global__ void build_relidx() {
    int i = blockIdx.x * blockDim.x + threadIdx.x;
    if (i >= 2047) return;
    int delta = i - 1023;
    int ad = delta < 0 ? -delta : delta;
    int bucket;
    if (ad <= 128) {
        bucket = delta;
    } else {
        float num = logf((float)ad / 128.0f);
        double v = (double)num / log(511.0 / 128.0) * 127.0;
        int lp = (int)ceil(v) + 128;
        bucket = (delta > 0) ? lp : -lp;
    }
    int idx = bucket + SPAN;
    idx = idx < 0 ? 0 : (idx > 511 ? 511 : idx);
    g_relidx[i] = idx;
}

// ---------------------------------------------------------------------------
// Kernel 2: C = A @ W^T + bias (all bf16 mirrors), C -> bf16 static buffer.
// 64x64 tile, BK=16, 256 threads, 4x4 per thread.
// ---------------------------------------------------------------------------
__device__ __forceinline__ const u16* asel(int s) { return s == 0 ? g_hid : g_rel; }
__device__ __forceinline__ const u16* wsel(int s) { return s == 0 ? g_Wq : (s == 1 ? g_Wk : g_Wv); }
__device__ __forceinline__ const u16* bsel(int s) { return s == 0 ? g_bq : (s == 1 ? g_bk : g_bv); }
__device__ __forceinline__ u16* csel(int s) {
    switch (s) {
        case 0: return g_q;
        case 1: return g_k;
        case 2: return g_v;
        case 3: return g_posk;
        default: return g_posq;
    }
}

__global__ __launch_bounds__(256) void gemm_bias_kernel(
    int a_sel, int w_sel, int out_sel, int M, int N, int K)
{
    const u16* __restrict__ A    = asel(a_sel);
    const u16* __restrict__ W    = wsel(w_sel);
    const u16* __restrict__ bias = bsel(w_sel);
    u16* __restrict__ C          = csel(out_sel);

    __shared__ float As[16][64];
    __shared__ float Ws[16][64];
    const int tid = threadIdx.x;
    const int tx = tid & 15;
    const int ty = tid >> 4;
    const int m0 = blockIdx.y * 64;
    const int n0 = blockIdx.x * 64;
    const int lr = tid >> 2;
    const int lk = (tid & 3) << 2;

    float acc[4][4] = {{0.f}};

    for (int k0 = 0; k0 < K; k0 += 16) {
        ushort4 av = *(const ushort4*)(A + (size_t)(m0 + lr) * K + k0 + lk);
        ushort4 wv = *(const ushort4*)(W + (size_t)(n0 + lr) * K + k0 + lk);
        As[lk + 0][lr] = b2f(av.x); As[lk + 1][lr] = b2f(av.y);
        As[lk + 2][lr] = b2f(av.z); As[lk + 3][lr] = b2f(av.w);
        Ws[lk + 0][lr] = b2f(wv.x); Ws[lk + 1][lr] = b2f(wv.y);
        Ws[lk + 2][lr] = b2f(wv.z); Ws[lk + 3][lr] = b2f(wv.w);
        __syncthreads();
        #pragma unroll
        for (int kk = 0; kk < 16; ++kk) {
            const float4 a4 = *(const float4*)&As[kk][ty << 2];
            const float4 w4 = *(const float4*)&Ws[kk][tx << 2];
            const float aa[4] = {a4.x, a4.y, a4.z, a4.w};
            const float ww[4] = {w4.x, w4.y, w4.z, w4.w};
            #pragma unroll
            for (int i = 0; i < 4; ++i)
                #pragma unroll
                for (int j = 0; j < 4; ++j)
                    acc[i][j] += aa[i] * ww[j];
        }
        __syncthreads();
    }

    #pragma unroll
    for (int i = 0; i < 4; ++i) {
        const int m = m0 + (ty << 2) + i;
        #pragma unroll
        for (int j = 0; j < 4; ++j) {
            const int n = n0 + (tx << 2) + j;
            C[(size_t)m * N + n] = f2b(acc[i][j] + b2f(bias[n]));
        }
    }
}

// ---------------------------------------------------------------------------
// Kernel 3: fused attention row.  One block (256 thr) per (b,h,s).
// probs written to d_out (+TOT elements) in flag-selected dtype.
// ---------------------------------------------------------------------------
__global__ __launch_bounds__(256) void attn_row_kernel(
    void* __restrict__ dout, int has_probs)
{
    const int s  = blockIdx.x;
    const int bh = blockIdx.y;
    const int b  = bh / NH;
    const int h  = bh % NH;
    const int tid = threadIdx.x;

    __shared__ float qs[DD];
    __shared__ float c2p[TWOSPAN];
    __shared__ float sc[SS];
    __shared__ float red[4];

    const size_t qbase = ((size_t)(b * SS + s)) * HH + h * DD;
    if (tid < DD) qs[tid] = b2f(g_q[qbase + tid]);
    __syncthreads();

    // phase 1: c2p[j] = q_s . posk[j]
    for (int j = tid; j < TWOSPAN; j += 256) {
        const u16* pk = g_posk + (size_t)j * HH + h * DD;
        float acc = 0.f;
        #pragma unroll
        for (int i = 0; i < 16; ++i) {
            const ushort4 pv = *(const ushort4*)(pk + i * 4);
            const float4 qv = *(const float4*)(qs + i * 4);
            acc += qv.x * b2f(pv.x) + qv.y * b2f(pv.y)
                 + qv.z * b2f(pv.z) + qv.w * b2f(pv.w);
        }
        c2p[j] = acc;
    }
    __syncthreads();

    // phase 2: scores (diagnostic clamp: no-op for valid data)
    const float rscale = 0.07216878364870323f;   // 1/sqrt(192)
    #pragma unroll
    for (int c = 0; c < 4; ++c) {
        const int t = c * 256 + tid;
        const u16* kp = g_k + ((size_t)(b * SS + t)) * HH + h * DD;
        const int j = g_relidx[s - t + 1023];
        const u16* pq = g_posq + (size_t)j * HH + h * DD;
        float a1 = 0.f, a2 = 0.f;
        #pragma unroll
        for (int i = 0; i < 16; ++i) {
            const ushort4 kv = *(const ushort4*)(kp + i * 4);
            const ushort4 pv = *(const ushort4*)(pq + i * 4);
            const float4 qv = *(const float4*)(qs + i * 4);
            const float k0 = b2f(kv.x), k1 = b2f(kv.y), k2 = b2f(kv.z), k3 = b2f(kv.w);
            a1 += qv.x * k0 + qv.y * k1 + qv.z * k2 + qv.w * k3;
            a2 += b2f(pv.x) * k0 + b2f(pv.y) * k1 + b2f(pv.z) * k2 + b2f(pv.w) * k3;
        }
        float val = (a1 + a2 + c2p[j]) * rscale;
        sc[t] = fminf(fmaxf(val, -30000.f), 30000.f);
    }
    __syncthreads();

    // phase 3: softmax
    float m = -1e30f;
    #pragma unroll
    for (int c = 0; c < 4; ++c) m = fmaxf(m, sc[c * 256 + tid]);
    #pragma unroll
    for (int off = 32; off > 0; off >>= 1) m = fmaxf(m, __shfl_down(m, off));
    if ((tid & 63) == 0) red[tid >> 6] = m;
    __syncthreads();
    if (tid == 0) red[0] = fmaxf(fmaxf(red[0], red[1]), fmaxf(red[2], red[3]));
    __syncthreads();
    const float rowmax = red[0];
    __syncthreads();

    float pvals[4];
    float ssum = 0.f;
    #pragma unroll
    for (int c = 0; c < 4; ++c) {
        const float e = __expf(sc[c * 256 + tid] - rowmax);
        pvals[c] = e;
        ssum += e;
    }
    #pragma unroll
    for (int off = 32; off > 0; off >>= 1) ssum += __shfl_down(ssum, off);
    if ((tid & 63) == 0) red[tid >> 6] = ssum;
    __syncthreads();
    if (tid == 0) red[0] = red[0] + red[1] + red[2] + red[3];
    __syncthreads();
    const float inv = 1.0f / red[0];

    const int isf = g_isfp32;
    const size_t pbase = ((size_t)bh * SS + s) * SS + (size_t)TOT;
    #pragma unroll
    for (int c = 0; c < 4; ++c) {
        const int t = c * 256 + tid;
        const float p = pvals[c] * inv;
        sc[t] = p;
        if (has_probs) {
            if (isf) ((float*)dout)[pbase + t] = p;
            else     ((u16*)dout)[pbase + t]   = f2b(p);
        }
    }
    __syncthreads();

    // phase 4: ctx = sum_t p_t * v_t
    const int d = tid & 63;
    const int g = tid >> 6;
    float acc = 0.f;
    const u16* vb = g_v + ((size_t)(b * SS)) * HH + h * DD + d;
    for (int t = g * 256; t < g * 256 + 256; ++t) {
        acc += sc[t] * b2f(vb[(size_t)t * HH]);
    }
    c2p[g * 64 + d] = acc;
    __syncthreads();
    if (tid < 64) {
        float r = c2p[tid] + c2p[64 + tid] + c2p[128 + tid] + c2p[192 + tid];
        r = fminf(fmaxf(r, -1e6f), 1e6f);
        g_ctx[qbase + tid] = f2b(r);
    }
}

// ---------------------------------------------------------------------------
// Kernel 4: out = LN( ctx @ Wo^T + bo + hidden ).  One block per token row.
// ---------------------------------------------------------------------------
__global__ __launch_bounds__(256) void out_ln_kernel(void* __restrict__ dout)
{
    const int row = blockIdx.x;
    const int tid = threadIdx.x;
    __shared__ float xs[HH];
    __shared__ float os[HH];
    __shared__ float red[4];

    for (int c = tid; c < HH; c += 256) xs[c] = b2f(g_ctx[(size_t)row * HH + c]);
    __syncthreads();

    for (int c = tid; c < HH; c += 256) {
        const u16* wrow = g_Wo + (size_t)c * HH;
        float acc = 0.f;
        #pragma unroll 8
        for (int i = 0; i < HH / 4; ++i) {
            const ushort4 wv = *(const ushort4*)(wrow + i * 4);
            const float4 xv = *(const float4*)(xs + i * 4);
            acc += xv.x * b2f(wv.x) + xv.y * b2f(wv.y)
                 + xv.z * b2f(wv.z) + xv.w * b2f(wv.w);
        }
        acc += b2f(g_bo[c]) + b2f(g_hid[(size_t)row * HH + c]);
        os[c] = fminf(fmaxf(acc, -1e6f), 1e6f);   // diagnostic clamp, no-op normally
    }
    __syncthreads();

    float sum = 0.f;
    for (int c = tid; c < HH; c += 256) sum += os[c];
    #pragma unroll
    for (int off = 32; off > 0; off >>= 1) sum += __shfl_down(sum, off);
    if ((tid & 63) == 0) red[tid >> 6] = sum;
    __syncthreads();
    if (tid == 0) red[0] = red[0] + red[1] + red[2] + red[3];
    __syncthreads();
    const float mu = red[0] * (1.0f / HH);
    __syncthreads();

    float vs = 0.f;
    for (int c = tid; c < HH; c += 256) {
        const float dd = os[c] - mu;
        vs += dd * dd;
    }
    #pragma unroll
    for (int off = 32; off > 0; off >>= 1) vs += __shfl_down(vs, off);
    if ((tid & 63) == 0) red[tid >> 6] = vs;
    __syncthreads();
    if (tid == 0) red[0] = red[0] + red[1] + red[2] + red[3];
    __syncthreads();
    const float var = red[0] * (1.0f / HH);
    const float rstd = 1.0f / sqrtf(var + 1e-7f);

    const int isf = g_isfp32;
    for (int c = tid; c < HH; c += 256) {
        const float o = b2f(g_lnw[c]) * (os[c] - mu) * rstd + b2f(g_lnb[c]);
        if (isf) ((float*)dout)[(size_t)row * HH + c] = o;
        else     ((u16*)dout)[(size_t)row * HH + c]   = f2b(o);
    }
}

// ---------------------------------------------------------------------------
extern "C" void kernel_launch(void* const* d_in, const int* in_sizes, int n_in,
                              void* d_out, int out_size, void* d_ws, size_t ws_size,
                              hipStream_t stream) {
    detect_dtype<<<1, 256, 0, stream>>>((const u16*)d_in[0]);

    // convert all inputs into bf16 mirrors (src order per setup_inputs)
    struct { const void* src; int n; int tgt; } cv[12] = {
        { d_in[0],  TOT,    0 }, { d_in[1],  POSTOT, 1 },
        { d_in[2],  WTOT,   2 }, { d_in[3],  HH,     3 },
        { d_in[4],  WTOT,   4 }, { d_in[5],  HH,     5 },
        { d_in[6],  WTOT,   6 }, { d_in[7],  HH,     7 },
        { d_in[8],  WTOT,   8 }, { d_in[9],  HH,     9 },
        { d_in[10], HH,    10 }, { d_in[11], HH,    11 },
    };
    // map tgt -> device symbol via per-target launches
    // (device globals can't be addressed host-side without symbol APIs)
    // so we use a small wrapper kernel per target
    {
        u16* dsts[12];
        // obtain device addresses once per call via a tiny launch-free trick:
        // hipGetSymbolAddress is a pure query, safe under graph capture.
        void* p;
        hipGetSymbolAddress(&p, HIP_SYMBOL(g_hid)); dsts[0] = (u16*)p;
        hipGetSymbolAddress(&p, HIP_SYMBOL(g_rel)); dsts[1] = (u16*)p;
        hipGetSymbolAddress(&p, HIP_SYMBOL(g_Wq));  dsts[2] = (u16*)p;
        hipGetSymbolAddress(&p, HIP_SYMBOL(g_bq));  dsts[3] = (u16*)p;
        hipGetSymbolAddress(&p, HIP_SYMBOL(g_Wk));  dsts[4] = (u16*)p;
        hipGetSymbolAddress(&p, HIP_SYMBOL(g_bk));  dsts[5] = (u16*)p;
        hipGetSymbolAddress(&p, HIP_SYMBOL(g_Wv));  dsts[6] = (u16*)p;
        hipGetSymbolAddress(&p, HIP_SYMBOL(g_bv));  dsts[7] = (u16*)p;
        hipGetSymbolAddress(&p, HIP_SYMBOL(g_Wo));  dsts[8] = (u16*)p;
        hipGetSymbolAddress(&p, HIP_SYMBOL(g_bo));  dsts[9] = (u16*)p;
        hipGetSymbolAddress(&p, HIP_SYMBOL(g_lnw)); dsts[10] = (u16*)p;
        hipGetSymbolAddress(&p, HIP_SYMBOL(g_lnb)); dsts[11] = (u16*)p;
        for (int i = 0; i < 12; ++i) {
            const int n = cv[i].n;
            convert_in<<<(n + 255) / 256, 256, 0, stream>>>(cv[i].src, dsts[i], n);
        }
    }

    build_relidx<<<8, 256, 0, stream>>>();

    const int M = BB * SS;   // 4096
    gemm_bias_kernel<<<dim3(HH / 64, M / 64), 256, 0, stream>>>(0, 0, 0, M, HH, HH);
    gemm_bias_kernel<<<dim3(HH / 64, M / 64), 256, 0, stream>>>(0, 1, 1, M, HH, HH);
    gemm_bias_kernel<<<dim3(HH / 64, M / 64), 256, 0, stream>>>(0, 2, 2, M, HH, HH);
    gemm_bias_kernel<<<dim3(HH / 64, TWOSPAN / 64), 256, 0, stream>>>(1, 1, 3, TWOSPAN, HH, HH);
    gemm_bias_kernel<<<dim3(HH / 64, TWOSPAN / 64), 256, 0, stream>>>(1, 0, 4, TWOSPAN, HH, HH);

    const long long need = (long long)TOT + (long long)BB * NH * SS * SS;
    const int has_probs = ((long long)out_size >= need) ? 1 : 0;
    attn_row_kernel<<<dim3(SS, BB * NH), 256, 0, stream>>>(d_out, has_probs);

    out_ln_kernel<<<BB * SS, 256, 0, stream>>>(d_out);
}